// Round 3
// baseline (681.211 us; speedup 1.0000x reference)
//
#include <hip/hip_runtime.h>
#include <math.h>
#include <stdint.h>

#define BB 32
#define SS 4096
#define HH 1024
#define CHUNKS 16
#define ROWS_PER_BLOCK (SS / CHUNKS)             // 256
#define WAVES 4
#define ROWS_PER_WAVE (ROWS_PER_BLOCK / WAVES)   // 64
#define TROWS 2                                  // rows per tile per wave
#define NTILES (ROWS_PER_WAVE / TROWS)           // 32

typedef __attribute__((address_space(3))) uint32_t lds_u32_t;
typedef const __attribute__((address_space(1))) uint32_t glb_u32_t;

// Stage TROWS rows (8 KiB) for this wave: 8 x global_load_lds dwordx4,
// each instruction moves 1 KiB (64 lanes x 16 B). gsrc includes +lane*4;
// ldst is the wave-uniform segment base (HW scatters lane i to base+i*16).
__device__ __forceinline__ void stage_tile(const float* gsrc, float* ldst) {
#pragma unroll
    for (int seg = 0; seg < 8; ++seg) {
        __builtin_amdgcn_global_load_lds(
            (glb_u32_t*)(gsrc + seg * 256),
            (lds_u32_t*)(ldst + seg * 256), 16, 0, 0);
    }
}

// pw = exp(tanh(s)); tanh via exp+rcp (branch-free). tanh bounds energy to
// [-1,1] so softmax needs no max subtraction.
__device__ __forceinline__ float softmax_w(float s) {
    float t  = __expf(2.0f * s);
    float th = 1.0f - 2.0f * __builtin_amdgcn_rcpf(t + 1.0f);
    return __expf(th);
}

// Fused energy + un-normalized softmax-weighted accumulation, one x pass.
// Async LDS staging, per-wave double buffer, no barrier in the hot loop:
// in-flight bytes decoupled from VGPR budget (Little's-law fix).
__global__ __launch_bounds__(256, 2) void attn_pass1(
    const float* __restrict__ x, const float* __restrict__ w,
    float* __restrict__ pc, float* __restrict__ pl)
{
    __shared__ float lds[2][WAVES][TROWS * HH];   // 64 KiB -> 2 blocks/CU

    const int tid  = threadIdx.x;
    const int wave = tid >> 6;
    const int lane = tid & 63;
    const int blk  = blockIdx.x;            // b*CHUNKS + chunk
    const int b    = blk / CHUNKS;
    const int chunk= blk % CHUNKS;

    const float* xw = x + (long long)b * SS * HH
                        + (long long)chunk * ROWS_PER_BLOCK * HH
                        + (long long)wave * ROWS_PER_WAVE * HH;
    const float* gsrc = xw + lane * 4;

    stage_tile(gsrc, &lds[0][wave][0]);      // prologue: tile 0 in flight

    float4 wv[4];
#pragma unroll
    for (int k = 0; k < 4; ++k)
        wv[k] = *(const float4*)(w + k * 256 + lane * 4);

    float4 acc[4];
#pragma unroll
    for (int k = 0; k < 4; ++k) acc[k] = make_float4(0.f, 0.f, 0.f, 0.f);
    float l = 0.f;

    for (int t = 0; t < NTILES; ++t) {
        const int cur = t & 1;
        if (t + 1 < NTILES) {
            stage_tile(gsrc + (long long)(t + 1) * TROWS * HH,
                       &lds[1 - cur][wave][0]);
            // wait for tile t's 8 loads; tile t+1's 8 stay in flight
            asm volatile("s_waitcnt vmcnt(8)" ::: "memory");
        } else {
            asm volatile("s_waitcnt vmcnt(0)" ::: "memory");
        }

        const float* lp = &lds[cur][wave][0] + lane * 4;
        float4 xv[TROWS][4];
#pragma unroll
        for (int u = 0; u < TROWS; ++u)
#pragma unroll
            for (int k = 0; k < 4; ++k)
                xv[u][k] = *(const float4*)(lp + u * HH + k * 256);

        float s[TROWS];
#pragma unroll
        for (int u = 0; u < TROWS; ++u) {
            float tacc = 0.f;
#pragma unroll
            for (int k = 0; k < 4; ++k) {
                tacc = fmaf(xv[u][k].x, wv[k].x, tacc);
                tacc = fmaf(xv[u][k].y, wv[k].y, tacc);
                tacc = fmaf(xv[u][k].z, wv[k].z, tacc);
                tacc = fmaf(xv[u][k].w, wv[k].w, tacc);
            }
            s[u] = tacc;
        }
        // 64-lane butterfly reduce, TROWS independent chains interleaved
#pragma unroll
        for (int off = 32; off >= 1; off >>= 1)
#pragma unroll
            for (int u = 0; u < TROWS; ++u)
                s[u] += __shfl_xor(s[u], off, 64);

#pragma unroll
        for (int u = 0; u < TROWS; ++u) {
            float pw = softmax_w(s[u]);
            l += pw;
#pragma unroll
            for (int k = 0; k < 4; ++k) {
                acc[k].x = fmaf(pw, xv[u][k].x, acc[k].x);
                acc[k].y = fmaf(pw, xv[u][k].y, acc[k].y);
                acc[k].z = fmaf(pw, xv[u][k].z, acc[k].z);
                acc[k].w = fmaf(pw, xv[u][k].w, acc[k].w);
            }
        }
    }

    // Epilogue: block reduce across the 4 waves, reusing staging LDS.
    __syncthreads();
    float* red  = &lds[0][0][0];     // 4 KiB*WAVES region for context partials
    float* redl = &lds[1][0][0];     // wave l partials
#pragma unroll
    for (int k = 0; k < 4; ++k)
        *(float4*)(red + wave * HH + k * 256 + lane * 4) = acc[k];
    if (lane == 0) redl[wave] = l;   // l is lane-replicated within a wave
    __syncthreads();

    float4 c = *(const float4*)(red + tid * 4);
#pragma unroll
    for (int wv2 = 1; wv2 < WAVES; ++wv2) {
        float4 o = *(const float4*)(red + wv2 * HH + tid * 4);
        c.x += o.x; c.y += o.y; c.z += o.z; c.w += o.w;
    }
    *(float4*)(pc + (long long)blk * HH + tid * 4) = c;
    if (tid == 0)
        pl[blk] = redl[0] + redl[1] + redl[2] + redl[3];
}

// Pass 2: combine CHUNKS partials per batch, normalize.
__global__ __launch_bounds__(256) void attn_pass2(
    const float* __restrict__ pc, const float* __restrict__ pl,
    float* __restrict__ out)
{
    const int b = blockIdx.x;
    const int t = threadIdx.x;
    float l = 0.f;
    float4 c = make_float4(0.f, 0.f, 0.f, 0.f);
#pragma unroll
    for (int i = 0; i < CHUNKS; ++i) {
        const int blk = b * CHUNKS + i;
        l += pl[blk];
        float4 o = *(const float4*)(pc + (long long)blk * HH + t * 4);
        c.x += o.x; c.y += o.y; c.z += o.z; c.w += o.w;
    }
    const float inv = 1.f / l;
    float4 r = make_float4(c.x * inv, c.y * inv, c.z * inv, c.w * inv);
    *(float4*)(out + (long long)b * HH + t * 4) = r;
}

extern "C" void kernel_launch(void* const* d_in, const int* in_sizes, int n_in,
                              void* d_out, int out_size, void* d_ws, size_t ws_size,
                              hipStream_t stream) {
    const float* x = (const float*)d_in[0];   // [B,S,H] fp32
    const float* w = (const float*)d_in[1];   // [H] fp32
    float* out = (float*)d_out;               // [B,H] fp32

    float* pc = (float*)d_ws;                           // [B*CHUNKS, H]
    float* pl = pc + (size_t)BB * CHUNKS * HH;          // [B*CHUNKS]

    attn_pass1<<<BB * CHUNKS, 256, 0, stream>>>(x, w, pc, pl);
    attn_pass2<<<BB, 256, 0, stream>>>(pc, pl, out);
}